// Round 16
// baseline (521.905 us; speedup 1.0000x reference)
//
#include <hip/hip_runtime.h>

#define NN 50000
#define MP 50176   // 196 * 256
#define DD 512
#define EE 800000
#define NSCAN 196  // ceil(NN/256)
#define SCB 3321   // ceil((EE+NN)/256) scatter blocks
#define CNTB 3125  // EE/256 count blocks
#define WTB 2560   // weight transpose blocks (1024+1024+512)
#define CVB 25088  // (MP*DD/4)/256 convert blocks
#define CSRTOT (EE + NN + 3 * NN + 64)   // padded CSR capacity (entries)

typedef unsigned short u16;
typedef __attribute__((ext_vector_type(4))) float f32x4;
typedef __attribute__((ext_vector_type(8))) __bf16 bf16x8;
typedef __attribute__((ext_vector_type(8))) short s16x8;
typedef __attribute__((ext_vector_type(4))) short s16x4;
typedef __attribute__((ext_vector_type(4))) int i32x4;   // clang vector (NT-builtin compatible)

typedef __attribute__((address_space(1))) const void GVoid;
typedef __attribute__((address_space(3))) void LVoid;

__device__ __forceinline__ u16 f2bf(float f) {
  union { float f; unsigned u; } x; x.f = f;
  unsigned r = x.u + 0x7fffu + ((x.u >> 16) & 1u);   // RTNE
  return (u16)(r >> 16);
}
__device__ __forceinline__ float bf2f(u16 b) {
  union { unsigned u; float f; } x; x.u = ((unsigned)b) << 16;
  return x.f;
}

// ---------------- count (standalone; cnt pre-zeroed by memset) ----------------

__global__ __launch_bounds__(256) void count_k(const int* __restrict__ dst, int* __restrict__ cnt) {
  int e = (int)blockIdx.x * 256 + threadIdx.x;   // EE = CNTB*256 exactly
  atomicAdd(&cnt[dst[e]], 1);
}

// --- 3-stage parallel exclusive scan over PADDED degrees (deg = cnt+1, pad to mult 4) ---

__global__ __launch_bounds__(256) void scan1_k(const int* __restrict__ cnt, int* __restrict__ bsum) {
  __shared__ int s[256];
  const int t = threadIdx.x;
  const int i = blockIdx.x * 256 + t;
  s[t] = (i < NN) ? ((cnt[i] + 1 + 3) & ~3) : 0;
  __syncthreads();
  for (int off = 128; off > 0; off >>= 1) {
    if (t < off) s[t] += s[t + off];
    __syncthreads();
  }
  if (t == 0) bsum[blockIdx.x] = s[0];
}

__global__ __launch_bounds__(256) void scan2_k(const int* __restrict__ bsum, int* __restrict__ boff) {
  __shared__ int s[256];
  const int t = threadIdx.x;
  const int v = (t < NSCAN) ? bsum[t] : 0;
  s[t] = v;
  __syncthreads();
  for (int off = 1; off < 256; off <<= 1) {    // inclusive Hillis-Steele
    int a = s[t];
    int b = (t >= off) ? s[t - off] : 0;
    __syncthreads();
    s[t] = a + b;
    __syncthreads();
  }
  if (t < NSCAN) boff[t] = s[t] - v;           // exclusive
}

__global__ __launch_bounds__(256) void scan3_k(const int* __restrict__ cnt, const int* __restrict__ boff,
                                               int* __restrict__ rowp, int* __restrict__ cursor,
                                               float* __restrict__ dinv) {
  __shared__ int s[256];
  const int t = threadIdx.x;
  const int i = blockIdx.x * 256 + t;
  const int v = (i < NN) ? (cnt[i] + 1) : 0;   // real degree incl self-loop
  const int pv = (v + 3) & ~3;                 // padded degree
  s[t] = pv;
  __syncthreads();
  for (int off = 1; off < 256; off <<= 1) {    // inclusive
    int a = s[t];
    int b = (t >= off) ? s[t - off] : 0;
    __syncthreads();
    s[t] = a + b;
    __syncthreads();
  }
  const int excl = s[t] - pv + boff[blockIdx.x];
  if (i < NN) {
    rowp[i] = excl; cursor[i] = excl;
    dinv[i] = rsqrtf((float)v);
  }
  if (i == NN - 1) rowp[NN] = excl + pv;
}

// ---------------- fused tail: scatter + weight transpose + convert_x (NO LDS) ----------------
// Scatter's atomic/random-write latency hides under the 150MB convert stream.
// csr entry: .x = src BYTE offset (src<<10), .y = weight bits.

__global__ __launch_bounds__(256) void scatgat_k(const int* __restrict__ src, const int* __restrict__ dst,
                                                 const float* __restrict__ dinv, int* __restrict__ cursor,
                                                 int2* __restrict__ csr,
                                                 const float* __restrict__ W1, u16* __restrict__ W1T,
                                                 const float* __restrict__ W2, u16* __restrict__ W2T,
                                                 const float* __restrict__ Wo, u16* __restrict__ WoT,
                                                 const float* __restrict__ x, u16* __restrict__ xb) {
  const int b = (int)blockIdx.x, t = threadIdx.x;
  if (b < SCB) {                               // ---- scatter ----
    int e = b * 256 + t;
    if (e < EE) {
      int d = dst[e], sn = src[e];
      int pos = atomicAdd(&cursor[d], 1);
      csr[pos] = make_int2(sn << 10, __float_as_int(dinv[sn] * dinv[d]));
    } else if (e < EE + NN) {
      int i = e - EE;                          // self-loop edge
      int pos = atomicAdd(&cursor[i], 1);
      float di = dinv[i];
      csr[pos] = make_int2(i << 10, __float_as_int(di * di));
    }
    return;
  }
  if (b < SCB + WTB) {                         // ---- weight transpose (coalesced read) ----
    int b0 = b - SCB;
    int idx, k, n;
    if (b0 < 1024)      { idx = b0 * 256 + t;          k = idx >> 9; n = idx & 511; W1T[n * 512 + k] = f2bf(W1[idx]); }
    else if (b0 < 2048) { idx = (b0 - 1024) * 256 + t; k = idx >> 9; n = idx & 511; W2T[n * 512 + k] = f2bf(W2[idx]); }
    else                { idx = (b0 - 2048) * 256 + t; k = idx >> 8; n = idx & 255; WoT[n * 512 + k] = f2bf(Wo[idx]); }
    return;
  }
  // ---- convert x f32 -> bf16, zero pad rows ----
  size_t i = ((size_t)(b - SCB - WTB) * 256 + t) * 4;
  if (i >= (size_t)MP * DD) return;
  s16x4 v;
  if (i < (size_t)NN * DD) {
    f32x4 f = *(const f32x4*)(x + i);
    v = (s16x4){ (short)f2bf(f.x), (short)f2bf(f.y), (short)f2bf(f.z), (short)f2bf(f.w) };
  } else {
    v = (s16x4){ 0, 0, 0, 0 };
  }
  *(s16x4*)(xb + i) = v;
}

// ---------------- 256x128-tile bf16 GEMM (8 waves, 48KB LDS, 3 blocks/CU, single round) ----------------

template<int OUT_BF16>
__global__ __launch_bounds__(512) void gemm256_k(const u16* __restrict__ A, const u16* __restrict__ BT,
                                                 void* __restrict__ Cv, const float* __restrict__ bias,
                                                 int M, int N) {
  const int nwg = (int)gridDim.x;              // divisible by 8
  const int id = (int)blockIdx.x;
  const int xcd = id & 7;
  const int idx = id >> 3;
  const int q = nwg >> 3;
  const int tile = xcd * q + idx;
  const int ntn = N >> 7;
  const int bm = tile / ntn;
  const int bn = tile % ntn;

  __shared__ u16 As[2][256 * 32];
  __shared__ u16 Bs[2][128 * 32];
  const int t = threadIdx.x;
  const int lane = t & 63;
  const int wid = t >> 6;                      // 0..7
  const int wm = wid >> 1;                     // 0..3 (row quadrant)
  const int wn = wid & 1;                      // 0..1 (col half)
  f32x4 acc[4][4] = {};
  const int r0 = t >> 2;                       // staging row 0..127
  const int kc = (t & 3) * 8;
  const u16* Ab = A + (size_t)bm * 256 * DD + (size_t)r0 * DD + kc;
  const u16* Bb = BT + (size_t)bn * 128 * DD + (size_t)r0 * DD + kc;

  auto stage = [&](int buf, int kt) {
    __builtin_amdgcn_global_load_lds((GVoid*)(Ab + kt),            (LVoid*)(&As[buf][t * 8]),        16, 0, 0);
    __builtin_amdgcn_global_load_lds((GVoid*)(Ab + 128 * DD + kt), (LVoid*)(&As[buf][4096 + t * 8]), 16, 0, 0);
    __builtin_amdgcn_global_load_lds((GVoid*)(Bb + kt),            (LVoid*)(&Bs[buf][t * 8]),        16, 0, 0);
  };

  stage(0, 0);
  __syncthreads();

  #pragma unroll 2
  for (int step = 0; step < 16; ++step) {
    const int cur = step & 1;
    if (step < 15) stage(cur ^ 1, (step + 1) * 32);
    bf16x8 af[4], bv[4];
    #pragma unroll
    for (int m = 0; m < 4; ++m)
      af[m] = *(const bf16x8*)&As[cur][(wm * 64 + m * 16 + (lane & 15)) * 32 + (lane >> 4) * 8];
    #pragma unroll
    for (int n = 0; n < 4; ++n)
      bv[n] = *(const bf16x8*)&Bs[cur][(wn * 64 + n * 16 + (lane & 15)) * 32 + (lane >> 4) * 8];
    #pragma unroll
    for (int m = 0; m < 4; ++m) {
      #pragma unroll
      for (int n = 0; n < 4; ++n)
        acc[m][n] = __builtin_amdgcn_mfma_f32_16x16x32_bf16(af[m], bv[n], acc[m][n], 0, 0, 0);
    }
    __syncthreads();
  }

  // C layout: col = lane&15, row = (lane>>4)*4 + reg
  const int rb = bm * 256 + wm * 64 + ((lane >> 4) * 4);
  const int cb = bn * 128 + wn * 64 + (lane & 15);
  #pragma unroll
  for (int m = 0; m < 4; ++m) {
    #pragma unroll
    for (int rr = 0; rr < 4; ++rr) {
      const int row = rb + m * 16 + rr;
      if (row < M) {
        #pragma unroll
        for (int n = 0; n < 4; ++n) {
          const int col = cb + n * 16;
          if (OUT_BF16) ((u16*)Cv)[(size_t)row * N + col] = f2bf(acc[m][n][rr]);
          else          ((float*)Cv)[(size_t)row * N + col] = acc[m][n][rr] + bias[col];
        }
      }
    }
  }
}

// ---------------- CSR aggregation: XCD-pinned 64-dim slices, 8 nodes/wave, s16x8 gathers ----------------
// NT hints: csr is a once-through stream, out is write-once -> keep both out of L2
// so the 6.4MB H working set gets more of the 4MB per-XCD L2.

__global__ __launch_bounds__(256) void aggregate_k(const u16* __restrict__ H, const int* __restrict__ rowp,
                                                   const int2* __restrict__ csr,
                                                   const float* __restrict__ bias,
                                                   u16* __restrict__ out) {
  const int slice = (int)blockIdx.x & 7;        // XCD-pinned dim slice
  const int grp = (int)blockIdx.x >> 3;         // node group 0..1562
  const int wid = threadIdx.x >> 6;
  const int lane = threadIdx.x & 63;
  const int g = lane >> 3;                      // node sub-group 0..7
  const int l = lane & 7;                       // dim sub-lane
  const int node = grp * 32 + wid * 8 + g;
  if (node >= NN) return;
  const int d0 = slice * 64 + l * 8;
  const int beg = rowp[node];
  const int rounds = (rowp[node + 1] - beg) >> 2;
  const char* Hb = (const char*)H + (size_t)d0 * 2;
  const i32x4* cp = (const i32x4*)(csr + beg);  // beg mult of 4 -> 32B aligned
  float a0 = 0.f, a1 = 0.f, a2 = 0.f, a3 = 0.f, a4 = 0.f, a5 = 0.f, a6 = 0.f, a7 = 0.f;

  i32x4 c01 = __builtin_nontemporal_load(cp);
  i32x4 c23 = __builtin_nontemporal_load(cp + 1);
  for (int b = 0; b < rounds; ++b) {
    const s16x8 v0 = *(const s16x8*)(Hb + c01.x);
    const s16x8 v1 = *(const s16x8*)(Hb + c01.z);
    const s16x8 v2 = *(const s16x8*)(Hb + c23.x);
    const s16x8 v3 = *(const s16x8*)(Hb + c23.z);
    const i32x4 n01 = __builtin_nontemporal_load(cp + 2 * b + 2);   // prefetch (overshoot lands in pad)
    const i32x4 n23 = __builtin_nontemporal_load(cp + 2 * b + 3);
    const float w0 = __int_as_float(c01.y), w1 = __int_as_float(c01.w);
    const float w2 = __int_as_float(c23.y), w3 = __int_as_float(c23.w);
    a0 += bf2f((u16)v0[0]) * w0 + bf2f((u16)v1[0]) * w1 + bf2f((u16)v2[0]) * w2 + bf2f((u16)v3[0]) * w3;
    a1 += bf2f((u16)v0[1]) * w0 + bf2f((u16)v1[1]) * w1 + bf2f((u16)v2[1]) * w2 + bf2f((u16)v3[1]) * w3;
    a2 += bf2f((u16)v0[2]) * w0 + bf2f((u16)v1[2]) * w1 + bf2f((u16)v2[2]) * w2 + bf2f((u16)v3[2]) * w3;
    a3 += bf2f((u16)v0[3]) * w0 + bf2f((u16)v1[3]) * w1 + bf2f((u16)v2[3]) * w2 + bf2f((u16)v3[3]) * w3;
    a4 += bf2f((u16)v0[4]) * w0 + bf2f((u16)v1[4]) * w1 + bf2f((u16)v2[4]) * w2 + bf2f((u16)v3[4]) * w3;
    a5 += bf2f((u16)v0[5]) * w0 + bf2f((u16)v1[5]) * w1 + bf2f((u16)v2[5]) * w2 + bf2f((u16)v3[5]) * w3;
    a6 += bf2f((u16)v0[6]) * w0 + bf2f((u16)v1[6]) * w1 + bf2f((u16)v2[6]) * w2 + bf2f((u16)v3[6]) * w3;
    a7 += bf2f((u16)v0[7]) * w0 + bf2f((u16)v1[7]) * w1 + bf2f((u16)v2[7]) * w2 + bf2f((u16)v3[7]) * w3;
    c01 = n01; c23 = n23;
  }

  s16x8 o;
  o[0] = (short)f2bf(fmaxf(a0 + bias[d0 + 0], 0.f));
  o[1] = (short)f2bf(fmaxf(a1 + bias[d0 + 1], 0.f));
  o[2] = (short)f2bf(fmaxf(a2 + bias[d0 + 2], 0.f));
  o[3] = (short)f2bf(fmaxf(a3 + bias[d0 + 3], 0.f));
  o[4] = (short)f2bf(fmaxf(a4 + bias[d0 + 4], 0.f));
  o[5] = (short)f2bf(fmaxf(a5 + bias[d0 + 5], 0.f));
  o[6] = (short)f2bf(fmaxf(a6 + bias[d0 + 6], 0.f));
  o[7] = (short)f2bf(fmaxf(a7 + bias[d0 + 7], 0.f));
  __builtin_nontemporal_store(o, (s16x8*)(out + (size_t)node * DD + d0));
}

// ---------------- launch ----------------

extern "C" void kernel_launch(void* const* d_in, const int* in_sizes, int n_in,
                              void* d_out, int out_size, void* d_ws, size_t ws_size,
                              hipStream_t stream) {
  const float* x    = (const float*)d_in[0];
  const int*   ei   = (const int*)d_in[1];
  const float* W1   = (const float*)d_in[2];
  const float* b1   = (const float*)d_in[3];
  const float* W2   = (const float*)d_in[4];
  const float* b2   = (const float*)d_in[5];
  const float* Wout = (const float*)d_in[6];
  const float* bout = (const float*)d_in[7];
  float* out = (float*)d_out;
  (void)in_sizes; (void)n_in; (void)out_size; (void)ws_size;

  char* ws = (char*)d_ws;
  size_t off = 0;
  auto alloc = [&](size_t bytes) -> char* {
    char* p = ws + off;
    off = (off + bytes + 255) & ~(size_t)255;
    return p;
  };
  u16*   xb   = (u16*)alloc((size_t)MP * DD * 2);   // activations bf16, zero pad rows
  u16*   H    = (u16*)alloc((size_t)NN * DD * 2);   // GEMM output bf16
  u16*   W1T  = (u16*)alloc(512 * 512 * 2);
  u16*   W2T  = (u16*)alloc(512 * 512 * 2);
  u16*   WoT  = (u16*)alloc(256 * 512 * 2);
  int*   cnt  = (int*)alloc(NN * 4);
  float* dinv = (float*)alloc(NN * 4);
  int*   rowp = (int*)alloc((NN + 1) * 4);
  int*   cur  = (int*)alloc(NN * 4);
  int2*  csr  = (int2*)alloc((size_t)CSRTOT * 8);
  int*   bsum = (int*)alloc(NSCAN * 4);
  int*   boff = (int*)alloc(NSCAN * 4);

  const int* srcp = ei;        // edge_index[0]
  const int* dstp = ei + EE;   // edge_index[1]

  (void)hipMemsetAsync(cnt, 0, NN * 4, stream);
  (void)hipMemsetAsync(csr, 0, (size_t)CSRTOT * 8, stream);   // pad slots -> (offset 0, weight 0)

  count_k<<<CNTB, 256, 0, stream>>>(dstp, cnt);
  scan1_k<<<NSCAN, 256, 0, stream>>>(cnt, bsum);
  scan2_k<<<1, 256, 0, stream>>>(bsum, boff);
  scan3_k<<<NSCAN, 256, 0, stream>>>(cnt, boff, rowp, cur, dinv);
  scatgat_k<<<SCB + WTB + CVB, 256, 0, stream>>>(srcp, dstp, dinv, cur, csr,
                                                 W1, W1T, W2, W2T, Wout, WoT, x, xb);

  const int agg_grid = ((NN + 31) / 32) * 8;    // 1563 node-groups x 8 XCD slices

  // layer 1: H = xb @ W1 ; xb = relu(agg(H) + b1)
  gemm256_k<1><<<(MP / 256) * (512 / 128), 512, 0, stream>>>(xb, W1T, (void*)H, nullptr, NN, 512);
  aggregate_k<<<agg_grid, 256, 0, stream>>>(H, rowp, csr, b1, xb);
  // layer 2
  gemm256_k<1><<<(MP / 256) * (512 / 128), 512, 0, stream>>>(xb, W2T, (void*)H, nullptr, NN, 512);
  aggregate_k<<<agg_grid, 256, 0, stream>>>(H, rowp, csr, b2, xb);
  // output layer (f32 out + bias)
  gemm256_k<0><<<(MP / 256) * (256 / 128), 512, 0, stream>>>(xb, WoT, (void*)out, bout, NN, 256);
}

// Round 17
// 420.548 us; speedup vs baseline: 1.2410x; 1.2410x over previous
//
#include <hip/hip_runtime.h>

#define NN 50000
#define MP 50176   // 196 * 256
#define DD 512
#define EE 800000
#define NSCAN 196  // ceil(NN/256)
#define SCB 3321   // ceil((EE+NN)/256) scatter blocks
#define CNTB 3125  // EE/256 count blocks
#define WTB 2560   // weight transpose blocks (1024+1024+512)
#define CVB 25088  // (MP*DD/4)/256 convert blocks
#define CSRTOT (EE + NN + 3 * NN + 64)   // padded CSR capacity (entries)

typedef unsigned short u16;
typedef __attribute__((ext_vector_type(4))) float f32x4;
typedef __attribute__((ext_vector_type(8))) __bf16 bf16x8;
typedef __attribute__((ext_vector_type(8))) short s16x8;
typedef __attribute__((ext_vector_type(4))) short s16x4;

typedef __attribute__((address_space(1))) const void GVoid;
typedef __attribute__((address_space(3))) void LVoid;

__device__ __forceinline__ u16 f2bf(float f) {
  union { float f; unsigned u; } x; x.f = f;
  unsigned r = x.u + 0x7fffu + ((x.u >> 16) & 1u);   // RTNE
  return (u16)(r >> 16);
}
__device__ __forceinline__ float bf2f(u16 b) {
  union { unsigned u; float f; } x; x.u = ((unsigned)b) << 16;
  return x.f;
}

// ---------------- count (standalone; cnt pre-zeroed by memset) ----------------

__global__ __launch_bounds__(256) void count_k(const int* __restrict__ dst, int* __restrict__ cnt) {
  int e = (int)blockIdx.x * 256 + threadIdx.x;   // EE = CNTB*256 exactly
  atomicAdd(&cnt[dst[e]], 1);
}

// --- 3-stage parallel exclusive scan over PADDED degrees (deg = cnt+1, pad to mult 4) ---

__global__ __launch_bounds__(256) void scan1_k(const int* __restrict__ cnt, int* __restrict__ bsum) {
  __shared__ int s[256];
  const int t = threadIdx.x;
  const int i = blockIdx.x * 256 + t;
  s[t] = (i < NN) ? ((cnt[i] + 1 + 3) & ~3) : 0;
  __syncthreads();
  for (int off = 128; off > 0; off >>= 1) {
    if (t < off) s[t] += s[t + off];
    __syncthreads();
  }
  if (t == 0) bsum[blockIdx.x] = s[0];
}

__global__ __launch_bounds__(256) void scan2_k(const int* __restrict__ bsum, int* __restrict__ boff) {
  __shared__ int s[256];
  const int t = threadIdx.x;
  const int v = (t < NSCAN) ? bsum[t] : 0;
  s[t] = v;
  __syncthreads();
  for (int off = 1; off < 256; off <<= 1) {    // inclusive Hillis-Steele
    int a = s[t];
    int b = (t >= off) ? s[t - off] : 0;
    __syncthreads();
    s[t] = a + b;
    __syncthreads();
  }
  if (t < NSCAN) boff[t] = s[t] - v;           // exclusive
}

__global__ __launch_bounds__(256) void scan3_k(const int* __restrict__ cnt, const int* __restrict__ boff,
                                               int* __restrict__ rowp, int* __restrict__ cursor,
                                               float* __restrict__ dinv) {
  __shared__ int s[256];
  const int t = threadIdx.x;
  const int i = blockIdx.x * 256 + t;
  const int v = (i < NN) ? (cnt[i] + 1) : 0;   // real degree incl self-loop
  const int pv = (v + 3) & ~3;                 // padded degree
  s[t] = pv;
  __syncthreads();
  for (int off = 1; off < 256; off <<= 1) {    // inclusive
    int a = s[t];
    int b = (t >= off) ? s[t - off] : 0;
    __syncthreads();
    s[t] = a + b;
    __syncthreads();
  }
  const int excl = s[t] - pv + boff[blockIdx.x];
  if (i < NN) {
    rowp[i] = excl; cursor[i] = excl;
    dinv[i] = rsqrtf((float)v);
  }
  if (i == NN - 1) rowp[NN] = excl + pv;
}

// ---------------- fused tail: scatter + weight transpose + convert_x (NO LDS) ----------------
// Scatter's atomic/random-write latency hides under the 150MB convert stream.
// csr entry: .x = src BYTE offset (src<<10), .y = weight bits.

__global__ __launch_bounds__(256) void scatgat_k(const int* __restrict__ src, const int* __restrict__ dst,
                                                 const float* __restrict__ dinv, int* __restrict__ cursor,
                                                 int2* __restrict__ csr,
                                                 const float* __restrict__ W1, u16* __restrict__ W1T,
                                                 const float* __restrict__ W2, u16* __restrict__ W2T,
                                                 const float* __restrict__ Wo, u16* __restrict__ WoT,
                                                 const float* __restrict__ x, u16* __restrict__ xb) {
  const int b = (int)blockIdx.x, t = threadIdx.x;
  if (b < SCB) {                               // ---- scatter ----
    int e = b * 256 + t;
    if (e < EE) {
      int d = dst[e], sn = src[e];
      int pos = atomicAdd(&cursor[d], 1);
      csr[pos] = make_int2(sn << 10, __float_as_int(dinv[sn] * dinv[d]));
    } else if (e < EE + NN) {
      int i = e - EE;                          // self-loop edge
      int pos = atomicAdd(&cursor[i], 1);
      float di = dinv[i];
      csr[pos] = make_int2(i << 10, __float_as_int(di * di));
    }
    return;
  }
  if (b < SCB + WTB) {                         // ---- weight transpose (coalesced read) ----
    int b0 = b - SCB;
    int idx, k, n;
    if (b0 < 1024)      { idx = b0 * 256 + t;          k = idx >> 9; n = idx & 511; W1T[n * 512 + k] = f2bf(W1[idx]); }
    else if (b0 < 2048) { idx = (b0 - 1024) * 256 + t; k = idx >> 9; n = idx & 511; W2T[n * 512 + k] = f2bf(W2[idx]); }
    else                { idx = (b0 - 2048) * 256 + t; k = idx >> 8; n = idx & 255; WoT[n * 512 + k] = f2bf(Wo[idx]); }
    return;
  }
  // ---- convert x f32 -> bf16, zero pad rows ----
  size_t i = ((size_t)(b - SCB - WTB) * 256 + t) * 4;
  if (i >= (size_t)MP * DD) return;
  s16x4 v;
  if (i < (size_t)NN * DD) {
    f32x4 f = *(const f32x4*)(x + i);
    v = (s16x4){ (short)f2bf(f.x), (short)f2bf(f.y), (short)f2bf(f.z), (short)f2bf(f.w) };
  } else {
    v = (s16x4){ 0, 0, 0, 0 };
  }
  *(s16x4*)(xb + i) = v;
}

// ---------------- 256x128-tile bf16 GEMM (8 waves, 48KB LDS, 3 blocks/CU, single round) ----------------

template<int OUT_BF16>
__global__ __launch_bounds__(512) void gemm256_k(const u16* __restrict__ A, const u16* __restrict__ BT,
                                                 void* __restrict__ Cv, const float* __restrict__ bias,
                                                 int M, int N) {
  const int nwg = (int)gridDim.x;              // divisible by 8
  const int id = (int)blockIdx.x;
  const int xcd = id & 7;
  const int idx = id >> 3;
  const int q = nwg >> 3;
  const int tile = xcd * q + idx;
  const int ntn = N >> 7;
  const int bm = tile / ntn;
  const int bn = tile % ntn;

  __shared__ u16 As[2][256 * 32];
  __shared__ u16 Bs[2][128 * 32];
  const int t = threadIdx.x;
  const int lane = t & 63;
  const int wid = t >> 6;                      // 0..7
  const int wm = wid >> 1;                     // 0..3 (row quadrant)
  const int wn = wid & 1;                      // 0..1 (col half)
  f32x4 acc[4][4] = {};
  const int r0 = t >> 2;                       // staging row 0..127
  const int kc = (t & 3) * 8;
  const u16* Ab = A + (size_t)bm * 256 * DD + (size_t)r0 * DD + kc;
  const u16* Bb = BT + (size_t)bn * 128 * DD + (size_t)r0 * DD + kc;

  auto stage = [&](int buf, int kt) {
    __builtin_amdgcn_global_load_lds((GVoid*)(Ab + kt),            (LVoid*)(&As[buf][t * 8]),        16, 0, 0);
    __builtin_amdgcn_global_load_lds((GVoid*)(Ab + 128 * DD + kt), (LVoid*)(&As[buf][4096 + t * 8]), 16, 0, 0);
    __builtin_amdgcn_global_load_lds((GVoid*)(Bb + kt),            (LVoid*)(&Bs[buf][t * 8]),        16, 0, 0);
  };

  stage(0, 0);
  __syncthreads();

  #pragma unroll 2
  for (int step = 0; step < 16; ++step) {
    const int cur = step & 1;
    if (step < 15) stage(cur ^ 1, (step + 1) * 32);
    bf16x8 af[4], bv[4];
    #pragma unroll
    for (int m = 0; m < 4; ++m)
      af[m] = *(const bf16x8*)&As[cur][(wm * 64 + m * 16 + (lane & 15)) * 32 + (lane >> 4) * 8];
    #pragma unroll
    for (int n = 0; n < 4; ++n)
      bv[n] = *(const bf16x8*)&Bs[cur][(wn * 64 + n * 16 + (lane & 15)) * 32 + (lane >> 4) * 8];
    #pragma unroll
    for (int m = 0; m < 4; ++m) {
      #pragma unroll
      for (int n = 0; n < 4; ++n)
        acc[m][n] = __builtin_amdgcn_mfma_f32_16x16x32_bf16(af[m], bv[n], acc[m][n], 0, 0, 0);
    }
    __syncthreads();
  }

  // C layout: col = lane&15, row = (lane>>4)*4 + reg
  const int rb = bm * 256 + wm * 64 + ((lane >> 4) * 4);
  const int cb = bn * 128 + wn * 64 + (lane & 15);
  #pragma unroll
  for (int m = 0; m < 4; ++m) {
    #pragma unroll
    for (int rr = 0; rr < 4; ++rr) {
      const int row = rb + m * 16 + rr;
      if (row < M) {
        #pragma unroll
        for (int n = 0; n < 4; ++n) {
          const int col = cb + n * 16;
          if (OUT_BF16) ((u16*)Cv)[(size_t)row * N + col] = f2bf(acc[m][n][rr]);
          else          ((float*)Cv)[(size_t)row * N + col] = acc[m][n][rr] + bias[col];
        }
      }
    }
  }
}

// ---------------- CSR aggregation: XCD-pinned 64-dim slices, 8 nodes/wave, s16x8 gathers ----------------
// R14-exact form (96.4us measured; terminally closed). Plain loads/stores — R16 proved
// NT hints regress (CSR has 8x L2 reuse across dim-slices; NT bypass costs more than
// the freed capacity gains).

__global__ __launch_bounds__(256) void aggregate_k(const u16* __restrict__ H, const int* __restrict__ rowp,
                                                   const int2* __restrict__ csr,
                                                   const float* __restrict__ bias,
                                                   u16* __restrict__ out) {
  const int slice = (int)blockIdx.x & 7;        // XCD-pinned dim slice
  const int grp = (int)blockIdx.x >> 3;         // node group 0..1562
  const int wid = threadIdx.x >> 6;
  const int lane = threadIdx.x & 63;
  const int g = lane >> 3;                      // node sub-group 0..7
  const int l = lane & 7;                       // dim sub-lane
  const int node = grp * 32 + wid * 8 + g;
  if (node >= NN) return;
  const int d0 = slice * 64 + l * 8;
  const int beg = rowp[node];
  const int rounds = (rowp[node + 1] - beg) >> 2;
  const char* Hb = (const char*)H + (size_t)d0 * 2;
  const int4* cp = (const int4*)(csr + beg);    // beg mult of 4 -> 32B aligned
  float a0 = 0.f, a1 = 0.f, a2 = 0.f, a3 = 0.f, a4 = 0.f, a5 = 0.f, a6 = 0.f, a7 = 0.f;

  int4 c01 = cp[0], c23 = cp[1];
  for (int b = 0; b < rounds; ++b) {
    const s16x8 v0 = *(const s16x8*)(Hb + c01.x);
    const s16x8 v1 = *(const s16x8*)(Hb + c01.z);
    const s16x8 v2 = *(const s16x8*)(Hb + c23.x);
    const s16x8 v3 = *(const s16x8*)(Hb + c23.z);
    const int4 n01 = cp[2 * b + 2], n23 = cp[2 * b + 3];   // prefetch (overshoot lands in pad)
    const float w0 = __int_as_float(c01.y), w1 = __int_as_float(c01.w);
    const float w2 = __int_as_float(c23.y), w3 = __int_as_float(c23.w);
    a0 += bf2f((u16)v0[0]) * w0 + bf2f((u16)v1[0]) * w1 + bf2f((u16)v2[0]) * w2 + bf2f((u16)v3[0]) * w3;
    a1 += bf2f((u16)v0[1]) * w0 + bf2f((u16)v1[1]) * w1 + bf2f((u16)v2[1]) * w2 + bf2f((u16)v3[1]) * w3;
    a2 += bf2f((u16)v0[2]) * w0 + bf2f((u16)v1[2]) * w1 + bf2f((u16)v2[2]) * w2 + bf2f((u16)v3[2]) * w3;
    a3 += bf2f((u16)v0[3]) * w0 + bf2f((u16)v1[3]) * w1 + bf2f((u16)v2[3]) * w2 + bf2f((u16)v3[3]) * w3;
    a4 += bf2f((u16)v0[4]) * w0 + bf2f((u16)v1[4]) * w1 + bf2f((u16)v2[4]) * w2 + bf2f((u16)v3[4]) * w3;
    a5 += bf2f((u16)v0[5]) * w0 + bf2f((u16)v1[5]) * w1 + bf2f((u16)v2[5]) * w2 + bf2f((u16)v3[5]) * w3;
    a6 += bf2f((u16)v0[6]) * w0 + bf2f((u16)v1[6]) * w1 + bf2f((u16)v2[6]) * w2 + bf2f((u16)v3[6]) * w3;
    a7 += bf2f((u16)v0[7]) * w0 + bf2f((u16)v1[7]) * w1 + bf2f((u16)v2[7]) * w2 + bf2f((u16)v3[7]) * w3;
    c01 = n01; c23 = n23;
  }

  s16x8 o;
  o[0] = (short)f2bf(fmaxf(a0 + bias[d0 + 0], 0.f));
  o[1] = (short)f2bf(fmaxf(a1 + bias[d0 + 1], 0.f));
  o[2] = (short)f2bf(fmaxf(a2 + bias[d0 + 2], 0.f));
  o[3] = (short)f2bf(fmaxf(a3 + bias[d0 + 3], 0.f));
  o[4] = (short)f2bf(fmaxf(a4 + bias[d0 + 4], 0.f));
  o[5] = (short)f2bf(fmaxf(a5 + bias[d0 + 5], 0.f));
  o[6] = (short)f2bf(fmaxf(a6 + bias[d0 + 6], 0.f));
  o[7] = (short)f2bf(fmaxf(a7 + bias[d0 + 7], 0.f));
  *(s16x8*)(out + (size_t)node * DD + d0) = o;
}

// ---------------- launch ----------------

extern "C" void kernel_launch(void* const* d_in, const int* in_sizes, int n_in,
                              void* d_out, int out_size, void* d_ws, size_t ws_size,
                              hipStream_t stream) {
  const float* x    = (const float*)d_in[0];
  const int*   ei   = (const int*)d_in[1];
  const float* W1   = (const float*)d_in[2];
  const float* b1   = (const float*)d_in[3];
  const float* W2   = (const float*)d_in[4];
  const float* b2   = (const float*)d_in[5];
  const float* Wout = (const float*)d_in[6];
  const float* bout = (const float*)d_in[7];
  float* out = (float*)d_out;
  (void)in_sizes; (void)n_in; (void)out_size; (void)ws_size;

  char* ws = (char*)d_ws;
  size_t off = 0;
  auto alloc = [&](size_t bytes) -> char* {
    char* p = ws + off;
    off = (off + bytes + 255) & ~(size_t)255;
    return p;
  };
  u16*   xb   = (u16*)alloc((size_t)MP * DD * 2);   // activations bf16, zero pad rows
  u16*   H    = (u16*)alloc((size_t)NN * DD * 2);   // GEMM output bf16
  u16*   W1T  = (u16*)alloc(512 * 512 * 2);
  u16*   W2T  = (u16*)alloc(512 * 512 * 2);
  u16*   WoT  = (u16*)alloc(256 * 512 * 2);
  int*   cnt  = (int*)alloc(NN * 4);
  float* dinv = (float*)alloc(NN * 4);
  int*   rowp = (int*)alloc((NN + 1) * 4);
  int*   cur  = (int*)alloc(NN * 4);
  int2*  csr  = (int2*)alloc((size_t)CSRTOT * 8);
  int*   bsum = (int*)alloc(NSCAN * 4);
  int*   boff = (int*)alloc(NSCAN * 4);

  const int* srcp = ei;        // edge_index[0]
  const int* dstp = ei + EE;   // edge_index[1]

  (void)hipMemsetAsync(cnt, 0, NN * 4, stream);
  (void)hipMemsetAsync(csr, 0, (size_t)CSRTOT * 8, stream);   // pad slots -> (offset 0, weight 0)

  count_k<<<CNTB, 256, 0, stream>>>(dstp, cnt);
  scan1_k<<<NSCAN, 256, 0, stream>>>(cnt, bsum);
  scan2_k<<<1, 256, 0, stream>>>(bsum, boff);
  scan3_k<<<NSCAN, 256, 0, stream>>>(cnt, boff, rowp, cur, dinv);
  scatgat_k<<<SCB + WTB + CVB, 256, 0, stream>>>(srcp, dstp, dinv, cur, csr,
                                                 W1, W1T, W2, W2T, Wout, WoT, x, xb);

  const int agg_grid = ((NN + 31) / 32) * 8;    // 1563 node-groups x 8 XCD slices

  // layer 1: H = xb @ W1 ; xb = relu(agg(H) + b1)
  gemm256_k<1><<<(MP / 256) * (512 / 128), 512, 0, stream>>>(xb, W1T, (void*)H, nullptr, NN, 512);
  aggregate_k<<<agg_grid, 256, 0, stream>>>(H, rowp, csr, b1, xb);
  // layer 2
  gemm256_k<1><<<(MP / 256) * (512 / 128), 512, 0, stream>>>(xb, W2T, (void*)H, nullptr, NN, 512);
  aggregate_k<<<agg_grid, 256, 0, stream>>>(H, rowp, csr, b2, xb);
  // output layer (f32 out + bias)
  gemm256_k<0><<<(MP / 256) * (256 / 128), 512, 0, stream>>>(xb, WoT, (void*)out, bout, NN, 256);
}